// Round 3
// baseline (182.920 us; speedup 1.0000x reference)
//
#include <hip/hip_runtime.h>
#include <cmath>

// Problem constants
#define Bsz 32
#define Lsz 256
#define Asz 20
#define NCHUNK 8        // p-chunks per i (32 p each)
#define PCH 32          // L / NCHUNK
#define GRP 8           // blocks staged per LDS group (8*400 = 3200 floats)
#define NGRP 4          // groups per chunk
#define BLK1 256        // k1 block: t = jg*32 + b (jg=t>>5 in 0..7, b=t&31)

// Workspace offsets (floats). Total ~1.43M floats = 5.7 MB.
#define OFF_G 0                                    // [c][i][j][b] p>i gather partials
#define OFF_C (NCHUNK*Lsz*Bsz*Asz)                 // [c][i][j]    b-independent (p<=i)
#define OFF_E (OFF_C + NCHUNK*Lsz*Asz)             // [c][i][b]    energy pair partials
#define OFF_RSQ (OFF_E + NCHUNK*Lsz*Bsz)           // [2048] per-wg sum w^2
#define OFF_RAB (OFF_RSQ + NCHUNK*Lsz)             // [2048] per-wg sum |w|
#define OFF_K2  (OFF_RAB + NCHUNK*Lsz)             // [L*B]  per-(i,b) lse-energy

// Kernel 1: stream all of w_pair once. Grid 2048 x 256 threads = exactly
// 8 wg/CU x 4 waves = 32 waves/CU -> single dispatch round (no tail).
// wg -> (i,c) pairing puts complementary gather loads (i,c)/(255-i,7-c) on
// the same CU so per-CU gather work is ~constant.
__global__ __launch_bounds__(BLK1, 8) void k1(const int* __restrict__ x,
                                              const float* __restrict__ wp,
                                              float* __restrict__ ws) {
  const int wg = blockIdx.x;
  const int u = ((wg >> 4) << 3) | (wg & 7);   // 0..1023
  const int h = (wg >> 3) & 1;
  const int i = h ? (255 - (u >> 3)) : (u >> 3);
  const int c = h ? (7 - (u & 7)) : (u & 7);

  const int t = threadIdx.x;
  const int b = t & 31;
  const int jg = t >> 5;    // 0..7

  __shared__ float blk[GRP * 400];            // 12.8 KB
  __shared__ unsigned char xs[PCH * Bsz];     // 1 KB, [dp][b]
  __shared__ int xi[Bsz];
  __shared__ float wred[8];

  const int pbase = c * PCH;
  for (int k = t; k < PCH * Bsz; k += BLK1) {
    int dp = k >> 5, bb = k & 31;
    xs[k] = (unsigned char)x[bb * Lsz + pbase + dp];
  }
  if (t < Bsz) xi[t] = x[t * Lsz + i];

  float aJ0 = 0.f, aJ1 = 0.f, aJ2 = 0.f, accE = 0.f, accC = 0.f;
  float rsq = 0.f, rab = 0.f;

  const float4* wrow4 = (const float4*)(wp + (size_t)(i * Lsz + pbase) * 400);
  const int j0 = jg * 20, j1 = (jg + 8) * 20, j2 = (jg + 16) * 20;

  for (int g = 0; g < NGRP; ++g) {
    __syncthreads();  // blk free from previous gather (iter 0: xs/xi visible)
    // stage 800 float4 = one group of 8 blocks; reg-stats for free
    {
      float4* bf4 = (float4*)blk;
      const float4* src = wrow4 + g * 800;
      for (int k = t; k < 800; k += BLK1) {
        float4 v = src[k];
        bf4[k] = v;
        rsq += v.x*v.x + v.y*v.y + v.z*v.z + v.w*v.w;
        rab += fabsf(v.x)+fabsf(v.y)+fabsf(v.z)+fabsf(v.w);
      }
    }
    __syncthreads();

    const int p0 = pbase + g * GRP;
    // accJ (all waves): p > i. <=40 consecutive LDS words per wave -> free.
    int pps = i + 1 - p0; if (pps < 0) pps = 0;
    for (int pp = pps; pp < GRP; ++pp) {
      int xv = xs[((g * GRP + pp) << 5) | b];
      const float* bp = blk + pp * 400 + xv;
      aJ0 += bp[j0];
      aJ1 += bp[j1];
      if (jg < 4) aJ2 += bp[j2];   // wave-uniform branch (waves 0,1 only)
    }
    // accE (wave 1, lanes 64..95): all p, b = t-64
    if (t >= 64 && t < 96) {
      const int be = t - 64;
      const int eb = xi[be] * Asz;
      for (int pp = 0; pp < GRP; ++pp) {
        int xv = xs[((g * GRP + pp) << 5) | be];
        accE += blk[pp * 400 + eb + xv];
      }
    }
    // accC (wave 2, lanes 128..147): p<i -> col 19; p==i -> diag
    if (t >= 128 && t < 148) {
      const int jj = t - 128;
      int pend = i - p0; if (pend > GRP) pend = GRP;
      for (int pp = 0; pp < pend; ++pp) accC += blk[pp * 400 + jj * Asz + 19];
      const int pd = i - p0;
      if (pd >= 0 && pd < GRP) accC += blk[pd * 400 + jj * (Asz + 1)];
    }
  }

  // stores: OFF_G is [c][i][j][b] -> lane-consecutive
  {
    float* G = ws + OFF_G + (size_t)(c * Lsz + i) * (Bsz * Asz);
    G[jg * 32 + b] = aJ0;
    G[(jg + 8) * 32 + b] = aJ1;
    if (jg < 4) G[(jg + 16) * 32 + b] = aJ2;
  }
  if (t >= 64 && t < 96)   ws[OFF_E + (c * Lsz + i) * Bsz + (t - 64)]  = accE;
  if (t >= 128 && t < 148) ws[OFF_C + (c * Lsz + i) * Asz + (t - 128)] = accC;

  // reg-stat reduction: wave shuffle, then 4 partials via LDS
  for (int s = 32; s >= 1; s >>= 1) {
    rsq += __shfl_down(rsq, s);
    rab += __shfl_down(rab, s);
  }
  if ((t & 63) == 0) { wred[t >> 6] = rsq; wred[4 + (t >> 6)] = rab; }
  __syncthreads();
  if (t == 0) {
    ws[OFF_RSQ + wg] = wred[0] + wred[1] + wred[2] + wred[3];
    ws[OFF_RAB + wg] = wred[4] + wred[5] + wred[6] + wred[7];
  }
}

// Kernel 2: one block per i (640 threads, t=j*32+b): assemble logits,
// logsumexp per (b), subtract energy, write per-(i,b) partial.
__global__ __launch_bounds__(640) void k2(const int* __restrict__ x,
                                          const float* __restrict__ wsng,
                                          const float* __restrict__ ws,
                                          float* __restrict__ wso) {
  const int i = blockIdx.x;
  const int t = threadIdx.x;
  const int j = t >> 5, b = t & 31;
  __shared__ float l[Bsz * 21];

  float v = wsng[i * Asz + j];
  #pragma unroll
  for (int c = 0; c < NCHUNK; ++c) {
    v += ws[OFF_C + (c * Lsz + i) * Asz + j];
    v += ws[OFF_G + (size_t)(c * Lsz + i) * (Bsz * Asz) + t];  // [j][b] == t
  }
  l[b * 21 + j] = v;
  __syncthreads();

  if (t < Bsz) {
    float m = -1e30f;
    #pragma unroll
    for (int jj = 0; jj < Asz; ++jj) m = fmaxf(m, l[t * 21 + jj]);
    float se = 0.f;
    #pragma unroll
    for (int jj = 0; jj < Asz; ++jj) se += __expf(l[t * 21 + jj] - m);
    float lse = m + __logf(se);
    float en = wsng[i * Asz + x[t * Lsz + i]];
    #pragma unroll
    for (int c = 0; c < NCHUNK; ++c) en += ws[OFF_E + (c * Lsz + i) * Bsz + t];
    wso[OFF_K2 + i * Bsz + t] = lse - en;
  }
}

// Kernel 3: final scalar.
__global__ __launch_bounds__(256) void k3(const float* __restrict__ wsng,
                                          const float* __restrict__ ws,
                                          float* __restrict__ out) {
  const int t = threadIdx.x;
  float ssq = 0.f, sab = 0.f;
  for (int k = t; k < Lsz * Asz; k += 256) {
    float v = wsng[k];
    ssq += v * v; sab += fabsf(v);
  }
  float psq = 0.f, pab = 0.f;
  for (int k = t; k < NCHUNK * Lsz; k += 256) {
    psq += ws[OFF_RSQ + k];
    pab += ws[OFF_RAB + k];
  }
  float fe = 0.f;
  for (int k = t; k < Lsz * Bsz; k += 256) fe += ws[OFF_K2 + k];

  const float LP = 51.0f;  // 0.2 * (L-1)
  float val = fe * (1.0f / Bsz) + (ssq + sab) + LP * (psq + pab);

  __shared__ float red[256];
  red[t] = val;
  __syncthreads();
  for (int s = 128; s >= 1; s >>= 1) {
    if (t < s) red[t] += red[t + s];
    __syncthreads();
  }
  if (t == 0) out[0] = red[0];
}

extern "C" void kernel_launch(void* const* d_in, const int* in_sizes, int n_in,
                              void* d_out, int out_size, void* d_ws, size_t ws_size,
                              hipStream_t stream) {
  const int*   x       = (const int*)d_in[0];
  const float* wsingle = (const float*)d_in[1];
  const float* wpair   = (const float*)d_in[2];
  float* ws  = (float*)d_ws;
  float* out = (float*)d_out;

  k1<<<Lsz * NCHUNK, BLK1, 0, stream>>>(x, wpair, ws);
  k2<<<Lsz, 640, 0, stream>>>(x, wsingle, ws, ws);
  k3<<<1, 256, 0, stream>>>(wsingle, ws, out);
}